// Round 1
// baseline (451.888 us; speedup 1.0000x reference)
//
#include <hip/hip_runtime.h>
#include <cstdint>
#include <cstddef>

// ============================================================================
// MaskGenerator — full JAX-semantics port.
// PRNG: threefry2x32, "partitionable" stream (JAX >= 0.5 default).
// If validation fails with O(1) absmax (warp/shift mismatch), flip
// JAX_PARTITIONABLE to 0 to get the legacy (pre-0.5) counter scheme.
// ============================================================================

#define JAX_PARTITIONABLE 1

typedef unsigned int u32;

#define Bd 256
#define Ld 512
#define Fd 64
#define Nd 32768            // Ld*Fd
#define HALF_BIG 4194304u   // (Bd*Ld*Fd)/2, for legacy random_bits pairing

struct U2 { u32 a, b; };

__device__ __forceinline__ u32 rotl32(u32 x, int r){ return (x << r) | (x >> (32 - r)); }

// Threefry-2x32, 20 rounds, exactly as jax/_src/prng.py
__device__ __forceinline__ U2 tf2x32(u32 k0, u32 k1, u32 x0, u32 x1){
  u32 ks2 = k0 ^ k1 ^ 0x1BD11BDAu;
  x0 += k0; x1 += k1;
#define TFR4(r0,r1,r2,r3) \
  x0 += x1; x1 = rotl32(x1, r0); x1 ^= x0; \
  x0 += x1; x1 = rotl32(x1, r1); x1 ^= x0; \
  x0 += x1; x1 = rotl32(x1, r2); x1 ^= x0; \
  x0 += x1; x1 = rotl32(x1, r3); x1 ^= x0;
  TFR4(13,15,26,6)  x0 += k1;  x1 += ks2 + 1u;
  TFR4(17,29,16,24) x0 += ks2; x1 += k0 + 2u;
  TFR4(13,15,26,6)  x0 += k0;  x1 += k1 + 3u;
  TFR4(17,29,16,24) x0 += k1;  x1 += ks2 + 4u;
  TFR4(13,15,26,6)  x0 += ks2; x1 += k0 + 5u;
#undef TFR4
  U2 r; r.a = x0; r.b = x1; return r;
}

// random_bits(key, 32, N)[i];  half = N/2 (all our N are even; legacy path only)
__device__ __forceinline__ u32 rb32(u32 k0, u32 k1, u32 i, u32 half){
#if JAX_PARTITIONABLE
  U2 r = tf2x32(k0, k1, 0u, i);
  return r.a ^ r.b;
#else
  if (i < half){ U2 r = tf2x32(k0, k1, i, i + half); return r.a; }
  U2 r = tf2x32(k0, k1, i - half, i); return r.b;
#endif
}

// jax.random.split(key, n)[j]
__device__ __forceinline__ U2 split_key(u32 k0, u32 k1, u32 j, u32 n){
#if JAX_PARTITIONABLE
  (void)n;
  return tf2x32(k0, k1, 0u, j);
#else
  u32 i0 = 2u*j, i1 = 2u*j + 1u;
  u32 w0, w1;
  { u32 c = (i0 < n) ? i0 : (i0 - n); U2 r = tf2x32(k0, k1, c, c + n); w0 = (i0 < n) ? r.a : r.b; }
  { u32 c = (i1 < n) ? i1 : (i1 - n); U2 r = tf2x32(k0, k1, c, c + n); w1 = (i1 < n) ? r.a : r.b; }
  U2 o; o.a = w0; o.b = w1; return o;
#endif
}

__device__ __forceinline__ float sigmoidf_(float x){ return 1.0f / (1.0f + expf(-x)); }
__device__ __forceinline__ float softplusf_(float x){ return fmaxf(x, 0.0f) + log1pf(expf(-fabsf(x))); }
__device__ __forceinline__ float leakyf_(float x){ return (x > 0.0f) ? x : 0.2f * x; }

// XLA f32 ErfInv (Giles polynomial) — matches lax.erf_inv on f32
__device__ __forceinline__ float erfinvf_(float x){
  float w = -log1pf(-x * x);
  float p;
  if (w < 5.0f){
    w -= 2.5f;
    p =               2.81022636e-08f;
    p = fmaf(p, w,    3.43273939e-07f);
    p = fmaf(p, w,   -3.5233877e-06f);
    p = fmaf(p, w,   -4.39150654e-06f);
    p = fmaf(p, w,    0.00021858087f);
    p = fmaf(p, w,   -0.00125372503f);
    p = fmaf(p, w,   -0.00417768164f);
    p = fmaf(p, w,    0.246640727f);
    p = fmaf(p, w,    1.50140941f);
  } else {
    w = sqrtf(w) - 3.0f;
    p =              -0.000200214257f;
    p = fmaf(p, w,    0.000100950558f);
    p = fmaf(p, w,    0.00134934322f);
    p = fmaf(p, w,   -0.00367342844f);
    p = fmaf(p, w,    0.00573950773f);
    p = fmaf(p, w,   -0.0076224613f);
    p = fmaf(p, w,    0.00943887047f);
    p = fmaf(p, w,    1.00167406f);
    p = fmaf(p, w,    2.83297682f);
  }
  return p * x;
}

__device__ __forceinline__ float uniform_from_bits(u32 bits){
  return __uint_as_float((bits >> 9) | 0x3f800000u) - 1.0f;   // [0,1)
}

// jax.random.normal element: u in [nextafter(-1,0), 1), sqrt(2)*erfinv(u)
__device__ __forceinline__ float normal_from_bits(u32 bits){
  float u01 = uniform_from_bits(bits);
  const float lo = -0.99999994f;                // nextafter(-1,0)
  float v = fmaf(u01, 2.0f, lo);                // (1.0 - lo) rounds to exactly 2.0f
  v = fmaxf(lo, v);
  return 1.41421356f * erfinvf_(v);
}

// _time_warp index, exact integer semantics of the reference
__device__ __forceinline__ int warp_idx_(int t, int wp, int sh){
  int tps = t + sh;
  int pos = (t >= wp) ? ((tps < Ld - 1) ? tps : (Ld - 1)) : t;
  int neg = ((t >= wp + sh) && (t < Ld + sh)) ? (t - sh) : t;
  return (sh > 0) ? pos : ((sh < 0) ? neg : t);
}

// ---------------------------------------------------------------------------
// K0: z normals (256x64) + wp/sh randint draws
// ---------------------------------------------------------------------------
__global__ __launch_bounds__(256) void k_init(float* __restrict__ z, int* __restrict__ wp,
                                              int* __restrict__ shv, const float* __restrict__ p_shift){
  int gid = blockIdx.x * 256 + threadIdx.x;
  U2 kz = split_key(0u, 42u, 0u, 5u);
  z[gid] = normal_from_bits(rb32(kz.a, kz.b, (u32)gid, 8192u));
  if (blockIdx.x == 0){
    int b = threadIdx.x;
    float s_shift = sigmoidf_(p_shift[0]);
    int wsteps = (int)(51.2f * s_shift);       // float32(512*0.1) * s_shift, trunc
    U2 kwp = split_key(0u, 42u, 2u, 5u);
    U2 ksh = split_key(0u, 42u, 3u, 5u);
    {
      U2 k1 = split_key(kwp.a, kwp.b, 0u, 2u);
      U2 k2 = split_key(kwp.a, kwp.b, 1u, 2u);
      u32 hi = rb32(k1.a, k1.b, (u32)b, 128u);
      u32 lo = rb32(k2.a, k2.b, (u32)b, 128u);
      u32 span = (u32)(Ld - 2 * wsteps);
      u32 mult = 65536u % span; mult = (mult * mult) % span;
      u32 off = ((hi % span) * mult + (lo % span)) % span;
      wp[b] = wsteps + (int)off;
    }
    {
      U2 k1 = split_key(ksh.a, ksh.b, 0u, 2u);
      U2 k2 = split_key(ksh.a, ksh.b, 1u, 2u);
      u32 hi = rb32(k1.a, k1.b, (u32)b, 128u);
      u32 lo = rb32(k2.a, k2.b, (u32)b, 128u);
      u32 span = (u32)(2 * wsteps + 1);
      u32 mult = 65536u % span; mult = (mult * mult) % span;
      u32 off = ((hi % span) * mult + (lo % span)) % span;
      shv[b] = -wsteps + (int)off;
    }
  }
}

// ---------------------------------------------------------------------------
// MLP chain (fp32, small)
// ---------------------------------------------------------------------------
__global__ __launch_bounds__(128) void k_mlp1(const float* __restrict__ z, const float* __restrict__ w1,
                                              const float* __restrict__ b1, float* __restrict__ h1){
  int b = blockIdx.x, n = threadIdx.x;
  const float* zr = z + b * 64;
  float acc = b1[n];
  #pragma unroll 8
  for (int k = 0; k < 64; ++k) acc = fmaf(zr[k], w1[k * 128 + n], acc);
  h1[b * 128 + n] = leakyf_(acc);
}

__global__ __launch_bounds__(256) void k_mlp2(const float* __restrict__ h1, const float* __restrict__ w2,
                                              const float* __restrict__ b2, float* __restrict__ h2){
  int b = blockIdx.x, n = threadIdx.x;
  const float* hr = h1 + b * 128;
  float acc = b2[n];
  #pragma unroll 8
  for (int k = 0; k < 128; ++k) acc = fmaf(hr[k], w2[k * 256 + n], acc);
  h2[b * 256 + n] = leakyf_(acc);
}

__global__ __launch_bounds__(256) void k_mlp3(const float* __restrict__ h2, const float* __restrict__ w3,
                                              const float* __restrict__ b3, float* __restrict__ h3T){
  int b = blockIdx.x, n = threadIdx.x;
  const float* hr = h2 + b * 256;
  float acc = b3[n];
  #pragma unroll 8
  for (int k = 0; k < 256; ++k) acc = fmaf(hr[k], w3[k * 256 + n], acc);
  h3T[n * 256 + b] = leakyf_(acc);   // stored transposed [k][b] for coalesced reads downstream
}

__global__ __launch_bounds__(256) void k_scale(const float* __restrict__ h3T, const float* __restrict__ wsc,
                                               const float* __restrict__ bsc, const float* __restrict__ p_scale,
                                               float* __restrict__ scl){
  int tid = threadIdx.x;
  int b = blockIdx.x * 4 + (tid >> 6);
  int f = tid & 63;
  float acc = bsc[f];
  for (int k = 0; k < 256; ++k) acc = fmaf(h3T[k * 256 + b], wsc[k * 64 + f], acc);
  float s_scale = sigmoidf_(p_scale[0]);
  scl[b * 64 + f] = 1.0f + (softplusf_(acc) - 0.5f) * 0.2f * s_scale;
}

// ---------------------------------------------------------------------------
// K5: freq augmentation. 8 (b,f)-series per block; DIF fwd (natural->bitrev),
// spectral dropout at bit-reversed position, DIT inv (bitrev->natural).
// Writes freq into d_out; k_big reads it back element-wise (same thread).
// ---------------------------------------------------------------------------
__global__ __launch_bounds__(256) void k_freq(const float* __restrict__ x, float* __restrict__ out,
                                              const float* __restrict__ p_shift){
  __shared__ float2 a[8][514];   // pad 512->514: de-conflicts the ff-fast load/store phases
  __shared__ float2 tw[256];
  const int tid = threadIdx.x;
  const int b = blockIdx.x >> 3;
  const int f0 = (blockIdx.x & 7) << 3;
  float s_shift = sigmoidf_(p_shift[0]);
  float s_mix = 1.0f - s_shift;
  float ratio = fminf(s_mix * 0.1f, 0.5f);
  U2 kf = split_key(0u, 42u, 4u, 5u);

  {
    float ang = -6.283185307179586f * ((float)tid / 512.0f);
    tw[tid] = make_float2(cosf(ang), sinf(ang));   // exp(-2*pi*i*tid/512)
  }
  const float* xb = x + ((size_t)b * Ld) * Fd + f0;
  for (int idx = tid; idx < 4096; idx += 256){
    int t = idx >> 3, ff = idx & 7;
    a[ff][t] = make_float2(xb[t * Fd + ff], 0.0f);
  }
  __syncthreads();

  // forward DIF: twiddle exp(-2pi i pos/m), m = 2^s
  for (int s = 9; s >= 1; --s){
    int half = 1 << (s - 1);
    for (int idx = tid; idx < 2048; idx += 256){
      int ser = idx >> 8, bi = idx & 255;
      int pos = bi & (half - 1);
      int g = bi >> (s - 1);
      int i1 = (g << s) + pos;
      int i2 = i1 + half;
      float2 u = a[ser][i1], v = a[ser][i2];
      a[ser][i1] = make_float2(u.x + v.x, u.y + v.y);
      float dx = u.x - v.x, dy = u.y - v.y;
      float2 w = tw[pos << (9 - s)];
      a[ser][i2] = make_float2(dx * w.x - dy * w.y, dx * w.y + dy * w.x);
    }
    __syncthreads();
  }

  // dropout: position p holds X[rev9(p)]
  for (int idx = tid; idx < 4096; idx += 256){
    int ser = idx >> 9, p = idx & 511;
    int k = (int)(__brev((u32)p) >> 23);
    u32 cnt = (u32)(((b * Ld) + k) * Fd + f0 + ser);
    float u01 = uniform_from_bits(rb32(kf.a, kf.b, cnt, HALF_BIG));
    if (!(u01 > ratio)) a[ser][p] = make_float2(0.0f, 0.0f);
  }
  __syncthreads();

  // inverse DIT: twiddle exp(+2pi i pos/m)
  for (int s = 1; s <= 9; ++s){
    int half = 1 << (s - 1);
    for (int idx = tid; idx < 2048; idx += 256){
      int ser = idx >> 8, bi = idx & 255;
      int pos = bi & (half - 1);
      int g = bi >> (s - 1);
      int i1 = (g << s) + pos;
      int i2 = i1 + half;
      float2 w = tw[pos << (9 - s)];
      float2 v = a[ser][i2];
      float tx_ = v.x * w.x + v.y * w.y;    // v * conj(w)
      float ty_ = v.y * w.x - v.x * w.y;
      float2 u = a[ser][i1];
      a[ser][i1] = make_float2(u.x + tx_, u.y + ty_);
      a[ser][i2] = make_float2(u.x - tx_, u.y - ty_);
    }
    __syncthreads();
  }

  bool pass = (s_mix < 0.01f);
  float* ob = out + ((size_t)b * Ld) * Fd + f0;
  for (int idx = tid; idx < 4096; idx += 256){
    int t = idx >> 3, ff = idx & 7;
    float v = a[ff][t].x * (1.0f / 512.0f);
    if (pass) v = xb[t * Fd + ff];
    ob[t * Fd + ff] = v;
  }
}

// ---------------------------------------------------------------------------
// K6: fused mask/noise GEMMs (256x256x32768, fp32) + full epilogue.
// Block = 64 b-rows x 64 n-cols (= exactly one l position), 256 thr, 4x4/thr.
// ---------------------------------------------------------------------------
__global__ __launch_bounds__(256) void k_big(
    const float* __restrict__ x,
    const float* __restrict__ wm, const float* __restrict__ bm,
    const float* __restrict__ wn, const float* __restrict__ bn,
    const float* __restrict__ h3T, const float* __restrict__ scl,
    const int* __restrict__ wp, const int* __restrict__ shv,
    const float* __restrict__ p_mask, const float* __restrict__ p_noise,
    const float* __restrict__ p_shift,
    float* __restrict__ out)
{
  __shared__ __align__(16) float lh[32][64];
  __shared__ __align__(16) float lm[32][64];
  __shared__ __align__(16) float ln[32][64];
  const int tid = threadIdx.x;
  const int tx = tid & 15;
  const int ty = tid >> 4;
  const int l  = blockIdx.x;       // n-tile of 64 == one sequence position
  const int n0 = l << 6;
  const int b0 = blockIdx.y << 6;

  float accm[4][4] = {{0.0f}};
  float accn[4][4] = {{0.0f}};

  for (int k0 = 0; k0 < 256; k0 += 32){
    __syncthreads();
    for (int idx = tid; idx < 2048; idx += 256){
      int kk = idx >> 6, j = idx & 63;
      int krow = k0 + kk;
      lh[kk][j] = h3T[krow * 256 + b0 + j];
      lm[kk][j] = wm[krow * Nd + n0 + j];
      ln[kk][j] = wn[krow * Nd + n0 + j];
    }
    __syncthreads();
    #pragma unroll
    for (int kk = 0; kk < 32; ++kk){
      const float4 av  = *(const float4*)&lh[kk][ty << 2];
      const float4 bmv = *(const float4*)&lm[kk][tx << 2];
      const float4 bnv = *(const float4*)&ln[kk][tx << 2];
      const float aa[4] = {av.x, av.y, av.z, av.w};
      const float mmv[4] = {bmv.x, bmv.y, bmv.z, bmv.w};
      const float nnv[4] = {bnv.x, bnv.y, bnv.z, bnv.w};
      #pragma unroll
      for (int ib = 0; ib < 4; ++ib){
        #pragma unroll
        for (int jn = 0; jn < 4; ++jn){
          accm[ib][jn] = fmaf(aa[ib], mmv[jn], accm[ib][jn]);
          accn[ib][jn] = fmaf(aa[ib], nnv[jn], accn[ib][jn]);
        }
      }
    }
  }

  // scalars (match reference order/precision in f32)
  float s_mask  = sigmoidf_(p_mask[0]);
  float s_noise = sigmoidf_(p_noise[0]);
  float s_shift = sigmoidf_(p_shift[0]);
  float s_mix   = 1.0f - s_shift;
  float wa = 1.0f - s_mix - s_shift;
  wa = fminf(fmaxf(wa, 0.1f), 0.8f);
  float wb = s_mix * 0.5f;
  float wc = s_shift * 0.5f;
  float tot = wa + wb + wc;
  wa /= tot; wb /= tot; wc /= tot;
  bool pass = (s_mix < 0.01f);

  U2 knk = split_key(0u, 42u, 1u, 5u);

  const float4 bm4 = *(const float4*)&bm[n0 + (tx << 2)];
  const float4 bn4 = *(const float4*)&bn[n0 + (tx << 2)];
  const float bmv[4] = {bm4.x, bm4.y, bm4.z, bm4.w};
  const float bnv[4] = {bn4.x, bn4.y, bn4.z, bn4.w};

  #pragma unroll
  for (int ib = 0; ib < 4; ++ib){
    int b = b0 + (ty << 2) + ib;
    int wi = warp_idx_(l, wp[b], shv[b]);
    const float* xrow = x + ((size_t)b * Ld + l) * Fd;
    const float* wrow = x + ((size_t)b * Ld + wi) * Fd;
    float* orow = out + ((size_t)b * Ld + l) * Fd;
    const float4 xv4 = *(const float4*)&xrow[tx << 2];
    const float4 wv4 = *(const float4*)&wrow[tx << 2];
    const float4 fq4 = *(const float4*)&orow[tx << 2];   // freq written by k_freq
    const float4 sc4 = *(const float4*)&scl[b * 64 + (tx << 2)];
    const float xv[4]  = {xv4.x, xv4.y, xv4.z, xv4.w};
    const float wv[4]  = {wv4.x, wv4.y, wv4.z, wv4.w};
    const float fqv[4] = {fq4.x, fq4.y, fq4.z, fq4.w};
    const float scv[4] = {sc4.x, sc4.y, sc4.z, sc4.w};
    float o[4];
    #pragma unroll
    for (int jn = 0; jn < 4; ++jn){
      int nidx = n0 + (tx << 2) + jn;
      float maskv = sigmoidf_(accm[ib][jn] + bmv[jn]);
      maskv = 1.0f - (1.0f - maskv) * s_mask * 0.3f;
      float nmag = softplusf_(accn[ib][jn] + bnv[jn]);
      u32 cnt = (u32)(b * Nd + nidx);
      float nr = normal_from_bits(rb32(knk.a, knk.b, cnt, HALF_BIG));
      float noise = nr * nmag * s_noise * 0.05f;
      float fq = pass ? xv[jn] : fqv[jn];
      float aug = fmaf(xv[jn] * maskv, scv[jn], noise);  // x*mask*scale + noise
      o[jn] = aug * wa + fq * wb + wv[jn] * wc;
    }
    *(float4*)&orow[tx << 2] = make_float4(o[0], o[1], o[2], o[3]);
  }
}

// ---------------------------------------------------------------------------
extern "C" void kernel_launch(void* const* d_in, const int* in_sizes, int n_in,
                              void* d_out, int out_size, void* d_ws, size_t ws_size,
                              hipStream_t stream)
{
  (void)in_sizes; (void)n_in; (void)out_size; (void)ws_size;
  const float* x   = (const float*)d_in[0];
  // d_in[1] = batch_size (unused)
  const float* w1  = (const float*)d_in[2];
  const float* b1  = (const float*)d_in[3];
  const float* w2  = (const float*)d_in[4];
  const float* b2  = (const float*)d_in[5];
  const float* w3  = (const float*)d_in[6];
  const float* b3  = (const float*)d_in[7];
  const float* wm  = (const float*)d_in[8];
  const float* bm  = (const float*)d_in[9];
  const float* wn  = (const float*)d_in[10];
  const float* bn  = (const float*)d_in[11];
  const float* wsc = (const float*)d_in[12];
  const float* bsc = (const float*)d_in[13];
  const float* pm  = (const float*)d_in[14];
  const float* pn  = (const float*)d_in[15];
  const float* psh = (const float*)d_in[16];
  const float* psc = (const float*)d_in[17];
  float* out = (float*)d_out;
  char* ws = (char*)d_ws;

  // ws layout (bytes): wp[256]i32 @0, sh[256]i32 @1024, z @2048 (64K),
  // h1 @67584 (128K), h2 @198656 (256K), h3T @460800 (256K), scl @722944 (64K)
  int*   wp  = (int*)(ws + 0);
  int*   shv = (int*)(ws + 1024);
  float* z   = (float*)(ws + 2048);
  float* h1  = (float*)(ws + 67584);
  float* h2  = (float*)(ws + 198656);
  float* h3T = (float*)(ws + 460800);
  float* scl = (float*)(ws + 722944);

  k_init <<<dim3(64),   dim3(256), 0, stream>>>(z, wp, shv, psh);
  k_mlp1 <<<dim3(256),  dim3(128), 0, stream>>>(z, w1, b1, h1);
  k_mlp2 <<<dim3(256),  dim3(256), 0, stream>>>(h1, w2, b2, h2);
  k_mlp3 <<<dim3(256),  dim3(256), 0, stream>>>(h2, w3, b3, h3T);
  k_scale<<<dim3(64),   dim3(256), 0, stream>>>(h3T, wsc, bsc, psc, scl);
  k_freq <<<dim3(2048), dim3(256), 0, stream>>>(x, out, psh);
  k_big  <<<dim3(512, 4), dim3(256), 0, stream>>>(x, wm, bm, wn, bn, h3T, scl,
                                                  wp, shv, pm, pn, psh, out);
}

// Round 2
// 431.064 us; speedup vs baseline: 1.0483x; 1.0483x over previous
//
#include <hip/hip_runtime.h>
#include <cstdint>
#include <cstddef>

// ============================================================================
// MaskGenerator — JAX-semantics port. R2: k_big rewritten as bf16 MFMA GEMM.
// PRNG: threefry2x32, "partitionable" stream (verified correct in R1).
// ============================================================================

typedef unsigned int u32;

#define Bd 256
#define Ld 512
#define Fd 64
#define Nd 32768            // Ld*Fd
#define HALF_BIG 4194304u

struct U2 { u32 a, b; };

__device__ __forceinline__ u32 rotl32(u32 x, int r){ return (x << r) | (x >> (32 - r)); }

// Threefry-2x32, 20 rounds, exactly as jax/_src/prng.py
__device__ __forceinline__ U2 tf2x32(u32 k0, u32 k1, u32 x0, u32 x1){
  u32 ks2 = k0 ^ k1 ^ 0x1BD11BDAu;
  x0 += k0; x1 += k1;
#define TFR4(r0,r1,r2,r3) \
  x0 += x1; x1 = rotl32(x1, r0); x1 ^= x0; \
  x0 += x1; x1 = rotl32(x1, r1); x1 ^= x0; \
  x0 += x1; x1 = rotl32(x1, r2); x1 ^= x0; \
  x0 += x1; x1 = rotl32(x1, r3); x1 ^= x0;
  TFR4(13,15,26,6)  x0 += k1;  x1 += ks2 + 1u;
  TFR4(17,29,16,24) x0 += ks2; x1 += k0 + 2u;
  TFR4(13,15,26,6)  x0 += k0;  x1 += k1 + 3u;
  TFR4(17,29,16,24) x0 += k1;  x1 += ks2 + 4u;
  TFR4(13,15,26,6)  x0 += ks2; x1 += k0 + 5u;
#undef TFR4
  U2 r; r.a = x0; r.b = x1; return r;
}

__device__ __forceinline__ u32 rb32(u32 k0, u32 k1, u32 i){
  U2 r = tf2x32(k0, k1, 0u, i);
  return r.a ^ r.b;
}

__device__ __forceinline__ U2 split_key(u32 k0, u32 k1, u32 j){
  return tf2x32(k0, k1, 0u, j);
}

__device__ __forceinline__ float sigmoidf_(float x){ return 1.0f / (1.0f + expf(-x)); }
__device__ __forceinline__ float softplusf_(float x){ return fmaxf(x, 0.0f) + log1pf(expf(-fabsf(x))); }
__device__ __forceinline__ float leakyf_(float x){ return (x > 0.0f) ? x : 0.2f * x; }

// XLA f32 ErfInv (Giles polynomial)
__device__ __forceinline__ float erfinvf_(float x){
  float w = -log1pf(-x * x);
  float p;
  if (w < 5.0f){
    w -= 2.5f;
    p =               2.81022636e-08f;
    p = fmaf(p, w,    3.43273939e-07f);
    p = fmaf(p, w,   -3.5233877e-06f);
    p = fmaf(p, w,   -4.39150654e-06f);
    p = fmaf(p, w,    0.00021858087f);
    p = fmaf(p, w,   -0.00125372503f);
    p = fmaf(p, w,   -0.00417768164f);
    p = fmaf(p, w,    0.246640727f);
    p = fmaf(p, w,    1.50140941f);
  } else {
    w = sqrtf(w) - 3.0f;
    p =              -0.000200214257f;
    p = fmaf(p, w,    0.000100950558f);
    p = fmaf(p, w,    0.00134934322f);
    p = fmaf(p, w,   -0.00367342844f);
    p = fmaf(p, w,    0.00573950773f);
    p = fmaf(p, w,   -0.0076224613f);
    p = fmaf(p, w,    0.00943887047f);
    p = fmaf(p, w,    1.00167406f);
    p = fmaf(p, w,    2.83297682f);
  }
  return p * x;
}

__device__ __forceinline__ float uniform_from_bits(u32 bits){
  return __uint_as_float((bits >> 9) | 0x3f800000u) - 1.0f;
}

__device__ __forceinline__ float normal_from_bits(u32 bits){
  float u01 = uniform_from_bits(bits);
  const float lo = -0.99999994f;
  float v = fmaf(u01, 2.0f, lo);
  v = fmaxf(lo, v);
  return 1.41421356f * erfinvf_(v);
}

__device__ __forceinline__ int warp_idx_(int t, int wp, int sh){
  int tps = t + sh;
  int pos = (t >= wp) ? ((tps < Ld - 1) ? tps : (Ld - 1)) : t;
  int neg = ((t >= wp + sh) && (t < Ld + sh)) ? (t - sh) : t;
  return (sh > 0) ? pos : ((sh < 0) ? neg : t);
}

// f32 -> bf16 (RNE), packed pair
__device__ __forceinline__ u32 pack_bf16_2(float a, float b){
  u32 ua = __float_as_uint(a), ub = __float_as_uint(b);
  u32 ra = (ua + 0x7FFFu + ((ua >> 16) & 1u)) >> 16;
  u32 rb = (ub + 0x7FFFu + ((ub >> 16) & 1u)) >> 16;
  return (ra & 0xFFFFu) | (rb << 16);
}

// ---------------------------------------------------------------------------
// K0: z normals (256x64) + wp/sh randint draws
// ---------------------------------------------------------------------------
__global__ __launch_bounds__(256) void k_init(float* __restrict__ z, int* __restrict__ wp,
                                              int* __restrict__ shv, const float* __restrict__ p_shift){
  int gid = blockIdx.x * 256 + threadIdx.x;
  U2 kz = split_key(0u, 42u, 0u);
  z[gid] = normal_from_bits(rb32(kz.a, kz.b, (u32)gid));
  if (blockIdx.x == 0){
    int b = threadIdx.x;
    float s_shift = sigmoidf_(p_shift[0]);
    int wsteps = (int)(51.2f * s_shift);
    U2 kwp = split_key(0u, 42u, 2u);
    U2 ksh = split_key(0u, 42u, 3u);
    {
      U2 k1 = split_key(kwp.a, kwp.b, 0u);
      U2 k2 = split_key(kwp.a, kwp.b, 1u);
      u32 hi = rb32(k1.a, k1.b, (u32)b);
      u32 lo = rb32(k2.a, k2.b, (u32)b);
      u32 span = (u32)(Ld - 2 * wsteps);
      u32 mult = 65536u % span; mult = (mult * mult) % span;
      u32 off = ((hi % span) * mult + (lo % span)) % span;
      wp[b] = wsteps + (int)off;
    }
    {
      U2 k1 = split_key(ksh.a, ksh.b, 0u);
      U2 k2 = split_key(ksh.a, ksh.b, 1u);
      u32 hi = rb32(k1.a, k1.b, (u32)b);
      u32 lo = rb32(k2.a, k2.b, (u32)b);
      u32 span = (u32)(2 * wsteps + 1);
      u32 mult = 65536u % span; mult = (mult * mult) % span;
      u32 off = ((hi % span) * mult + (lo % span)) % span;
      shv[b] = -wsteps + (int)off;
    }
  }
}

// ---------------------------------------------------------------------------
// MLP chain (fp32, small).  h3 stored ROW-MAJOR [b][k] for MFMA A staging.
// ---------------------------------------------------------------------------
__global__ __launch_bounds__(128) void k_mlp1(const float* __restrict__ z, const float* __restrict__ w1,
                                              const float* __restrict__ b1, float* __restrict__ h1){
  int b = blockIdx.x, n = threadIdx.x;
  const float* zr = z + b * 64;
  float acc = b1[n];
  #pragma unroll 8
  for (int k = 0; k < 64; ++k) acc = fmaf(zr[k], w1[k * 128 + n], acc);
  h1[b * 128 + n] = leakyf_(acc);
}

__global__ __launch_bounds__(256) void k_mlp2(const float* __restrict__ h1, const float* __restrict__ w2,
                                              const float* __restrict__ b2, float* __restrict__ h2){
  int b = blockIdx.x, n = threadIdx.x;
  const float* hr = h1 + b * 128;
  float acc = b2[n];
  #pragma unroll 8
  for (int k = 0; k < 128; ++k) acc = fmaf(hr[k], w2[k * 256 + n], acc);
  h2[b * 256 + n] = leakyf_(acc);
}

__global__ __launch_bounds__(256) void k_mlp3(const float* __restrict__ h2, const float* __restrict__ w3,
                                              const float* __restrict__ b3, float* __restrict__ h3){
  int b = blockIdx.x, n = threadIdx.x;
  const float* hr = h2 + b * 256;
  float acc = b3[n];
  #pragma unroll 8
  for (int k = 0; k < 256; ++k) acc = fmaf(hr[k], w3[k * 256 + n], acc);
  h3[b * 256 + n] = leakyf_(acc);   // row-major [b][k]
}

__global__ __launch_bounds__(256) void k_scale(const float* __restrict__ h3, const float* __restrict__ wsc,
                                               const float* __restrict__ bsc, const float* __restrict__ p_scale,
                                               float* __restrict__ scl){
  int tid = threadIdx.x;
  int b = blockIdx.x * 4 + (tid >> 6);
  int f = tid & 63;
  float acc = bsc[f];
  for (int k = 0; k < 256; ++k) acc = fmaf(h3[b * 256 + k], wsc[k * 64 + f], acc);
  float s_scale = sigmoidf_(p_scale[0]);
  scl[b * 64 + f] = 1.0f + (softplusf_(acc) - 0.5f) * 0.2f * s_scale;
}

// ---------------------------------------------------------------------------
// K5: freq augmentation (unchanged from R1 — next round's target)
// ---------------------------------------------------------------------------
__global__ __launch_bounds__(256) void k_freq(const float* __restrict__ x, float* __restrict__ out,
                                              const float* __restrict__ p_shift){
  __shared__ float2 a[8][514];
  __shared__ float2 tw[256];
  const int tid = threadIdx.x;
  const int b = blockIdx.x >> 3;
  const int f0 = (blockIdx.x & 7) << 3;
  float s_shift = sigmoidf_(p_shift[0]);
  float s_mix = 1.0f - s_shift;
  float ratio = fminf(s_mix * 0.1f, 0.5f);
  U2 kf = split_key(0u, 42u, 4u);

  {
    float ang = -6.283185307179586f * ((float)tid / 512.0f);
    tw[tid] = make_float2(cosf(ang), sinf(ang));
  }
  const float* xb = x + ((size_t)b * Ld) * Fd + f0;
  for (int idx = tid; idx < 4096; idx += 256){
    int t = idx >> 3, ff = idx & 7;
    a[ff][t] = make_float2(xb[t * Fd + ff], 0.0f);
  }
  __syncthreads();

  for (int s = 9; s >= 1; --s){
    int half = 1 << (s - 1);
    for (int idx = tid; idx < 2048; idx += 256){
      int ser = idx >> 8, bi = idx & 255;
      int pos = bi & (half - 1);
      int g = bi >> (s - 1);
      int i1 = (g << s) + pos;
      int i2 = i1 + half;
      float2 u = a[ser][i1], v = a[ser][i2];
      a[ser][i1] = make_float2(u.x + v.x, u.y + v.y);
      float dx = u.x - v.x, dy = u.y - v.y;
      float2 w = tw[pos << (9 - s)];
      a[ser][i2] = make_float2(dx * w.x - dy * w.y, dx * w.y + dy * w.x);
    }
    __syncthreads();
  }

  for (int idx = tid; idx < 4096; idx += 256){
    int ser = idx >> 9, p = idx & 511;
    int k = (int)(__brev((u32)p) >> 23);
    u32 cnt = (u32)(((b * Ld) + k) * Fd + f0 + ser);
    float u01 = uniform_from_bits(rb32(kf.a, kf.b, cnt));
    if (!(u01 > ratio)) a[ser][p] = make_float2(0.0f, 0.0f);
  }
  __syncthreads();

  for (int s = 1; s <= 9; ++s){
    int half = 1 << (s - 1);
    for (int idx = tid; idx < 2048; idx += 256){
      int ser = idx >> 8, bi = idx & 255;
      int pos = bi & (half - 1);
      int g = bi >> (s - 1);
      int i1 = (g << s) + pos;
      int i2 = i1 + half;
      float2 w = tw[pos << (9 - s)];
      float2 v = a[ser][i2];
      float tx_ = v.x * w.x + v.y * w.y;
      float ty_ = v.y * w.x - v.x * w.y;
      float2 u = a[ser][i1];
      a[ser][i1] = make_float2(u.x + tx_, u.y + ty_);
      a[ser][i2] = make_float2(u.x - tx_, u.y - ty_);
    }
    __syncthreads();
  }

  bool pass = (s_mix < 0.01f);
  float* ob = out + ((size_t)b * Ld) * Fd + f0;
  for (int idx = tid; idx < 4096; idx += 256){
    int t = idx >> 3, ff = idx & 7;
    float v = a[ff][t].x * (1.0f / 512.0f);
    if (pass) v = xb[t * Fd + ff];
    ob[t * Fd + ff] = v;
  }
}

// ---------------------------------------------------------------------------
// K6: bf16 MFMA dual-GEMM (256x32768x256, x2) + fused epilogue.
// Block: 128 b-rows x 64 n-cols (one l). 4 waves, each 64b x 32n x 2 GEMMs.
// LDS tiles bf16, row stride 20 dwords (16B-aligned, bank-spread).
// A-frag: A[m=lane&15][k=quad*8+j]; B-frag mirrored; C: col=lane&15,
// row=quad*4+reg (guide §3, HW-verified m89/m91).
// ---------------------------------------------------------------------------
typedef short short8 __attribute__((ext_vector_type(8)));
typedef float f32x4 __attribute__((ext_vector_type(4)));

union Frag { uint4 u; short8 s; };

__global__ __launch_bounds__(256) void k_big(
    const float* __restrict__ x,
    const float* __restrict__ wm, const float* __restrict__ bm,
    const float* __restrict__ wn, const float* __restrict__ bn,
    const float* __restrict__ h3, const float* __restrict__ scl,
    const int* __restrict__ wp, const int* __restrict__ shv,
    const float* __restrict__ p_mask, const float* __restrict__ p_noise,
    const float* __restrict__ p_shift,
    float* __restrict__ out)
{
  __shared__ __align__(16) u32 As[128 * 20];      // [b][k/2], 16 data dwords + 4 pad
  __shared__ __align__(16) u32 Bs[2][64 * 20];    // [g][n][k/2]

  const int tid  = threadIdx.x;
  const int lane = tid & 63;
  const int w    = tid >> 6;
  const int q    = lane >> 4;
  const int lo   = lane & 15;
  const int l    = blockIdx.x;          // one sequence position per block
  const int n0   = l << 6;
  const int b0   = blockIdx.y << 7;     // 128 batch rows
  const int woffm = (w >> 1) << 6;      // 0 or 64
  const int woffn = (w & 1) << 5;       // 0 or 32

  f32x4 accm[4][2];
  f32x4 accn[4][2];
  #pragma unroll
  for (int i = 0; i < 4; ++i)
    #pragma unroll
    for (int j = 0; j < 2; ++j){ accm[i][j] = (f32x4)0.0f; accn[i][j] = (f32x4)0.0f; }

  // staging decomposition
  const int ar   = tid >> 1;            // A row 0..127
  const int ah   = tid & 1;             // A k-half (16 floats)
  const int nq   = tid & 15;            // B n-quad
  const int kp   = tid >> 4;            // B k-pair 0..15

  for (int kc = 0; kc < 256; kc += 32){
    if (kc) __syncthreads();
    // ---- stage A (h3[b][k] -> bf16 LDS, no transpose) ----
    {
      const float* g = h3 + (b0 + ar) * 256 + kc + ah * 16;
      float4 f0 = *(const float4*)(g + 0);
      float4 f1 = *(const float4*)(g + 4);
      float4 f2 = *(const float4*)(g + 8);
      float4 f3 = *(const float4*)(g + 12);
      uint4 q0, q1;
      q0.x = pack_bf16_2(f0.x, f0.y); q0.y = pack_bf16_2(f0.z, f0.w);
      q0.z = pack_bf16_2(f1.x, f1.y); q0.w = pack_bf16_2(f1.z, f1.w);
      q1.x = pack_bf16_2(f2.x, f2.y); q1.y = pack_bf16_2(f2.z, f2.w);
      q1.z = pack_bf16_2(f3.x, f3.y); q1.w = pack_bf16_2(f3.z, f3.w);
      u32* dst = &As[ar * 20 + ah * 8];
      *(uint4*)(dst + 0) = q0;
      *(uint4*)(dst + 4) = q1;
    }
    // ---- stage B (wm/wn [k][n] -> [n][k] bf16 LDS, transpose via regs) ----
    {
      size_t base = (size_t)(kc + 2 * kp) * Nd + n0 + (nq << 2);
      float4 m0 = *(const float4*)(wm + base);
      float4 m1 = *(const float4*)(wm + base + Nd);
      float4 v0 = *(const float4*)(wn + base);
      float4 v1 = *(const float4*)(wn + base + Nd);
      int nb = nq << 2;
      Bs[0][(nb + 0) * 20 + kp] = pack_bf16_2(m0.x, m1.x);
      Bs[0][(nb + 1) * 20 + kp] = pack_bf16_2(m0.y, m1.y);
      Bs[0][(nb + 2) * 20 + kp] = pack_bf16_2(m0.z, m1.z);
      Bs[0][(nb + 3) * 20 + kp] = pack_bf16_2(m0.w, m1.w);
      Bs[1][(nb + 0) * 20 + kp] = pack_bf16_2(v0.x, v1.x);
      Bs[1][(nb + 1) * 20 + kp] = pack_bf16_2(v0.y, v1.y);
      Bs[1][(nb + 2) * 20 + kp] = pack_bf16_2(v0.z, v1.z);
      Bs[1][(nb + 3) * 20 + kp] = pack_bf16_2(v0.w, v1.w);
    }
    __syncthreads();

    // ---- fragments + MFMA ----
    Frag af[4], bf[2][2];
    #pragma unroll
    for (int mt = 0; mt < 4; ++mt)
      af[mt].u = *(const uint4*)&As[(woffm + mt * 16 + lo) * 20 + q * 4];
    #pragma unroll
    for (int nt = 0; nt < 2; ++nt){
      bf[nt][0].u = *(const uint4*)&Bs[0][(woffn + nt * 16 + lo) * 20 + q * 4];
      bf[nt][1].u = *(const uint4*)&Bs[1][(woffn + nt * 16 + lo) * 20 + q * 4];
    }
    #pragma unroll
    for (int mt = 0; mt < 4; ++mt){
      #pragma unroll
      for (int nt = 0; nt < 2; ++nt){
        accm[mt][nt] = __builtin_amdgcn_mfma_f32_16x16x32_bf16(af[mt].s, bf[nt][0].s, accm[mt][nt], 0, 0, 0);
        accn[mt][nt] = __builtin_amdgcn_mfma_f32_16x16x32_bf16(af[mt].s, bf[nt][1].s, accn[mt][nt], 0, 0, 0);
      }
    }
  }

  // ---- epilogue ----
  float s_mask  = sigmoidf_(p_mask[0]);
  float s_noise = sigmoidf_(p_noise[0]);
  float s_shift = sigmoidf_(p_shift[0]);
  float s_mix   = 1.0f - s_shift;
  float wa = 1.0f - s_mix - s_shift;
  wa = fminf(fmaxf(wa, 0.1f), 0.8f);
  float wb = s_mix * 0.5f;
  float wc = s_shift * 0.5f;
  float tot = wa + wb + wc;
  wa /= tot; wb /= tot; wc /= tot;
  bool pass = (s_mix < 0.01f);

  U2 knk = split_key(0u, 42u, 1u);

  #pragma unroll
  for (int nt = 0; nt < 2; ++nt){
    int f = woffn + nt * 16 + lo;
    int nidx = n0 + f;
    float bmv = bm[nidx];
    float bnv = bn[nidx];
    #pragma unroll
    for (int mt = 0; mt < 4; ++mt){
      #pragma unroll
      for (int r = 0; r < 4; ++r){
        int b = b0 + woffm + mt * 16 + q * 4 + r;
        int wi = warp_idx_(l, wp[b], shv[b]);
        const float* xrow = x + ((size_t)b * Ld + l) * Fd;
        const float* wrow = x + ((size_t)b * Ld + wi) * Fd;
        float* orow = out + ((size_t)b * Ld + l) * Fd;
        float xv = xrow[f];
        float wv = wrow[f];
        float fq = pass ? xv : orow[f];
        float sc = scl[b * 64 + f];
        float maskv = sigmoidf_(accm[mt][nt][r] + bmv);
        maskv = 1.0f - (1.0f - maskv) * s_mask * 0.3f;
        float nmag = softplusf_(accn[mt][nt][r] + bnv);
        u32 cnt = (u32)(b * Nd + nidx);
        float nr = normal_from_bits(rb32(knk.a, knk.b, cnt));
        float noise = nr * nmag * s_noise * 0.05f;
        float aug = fmaf(xv * maskv, sc, noise);
        orow[f] = aug * wa + fq * wb + wv * wc;
      }
    }
  }
}

// ---------------------------------------------------------------------------
extern "C" void kernel_launch(void* const* d_in, const int* in_sizes, int n_in,
                              void* d_out, int out_size, void* d_ws, size_t ws_size,
                              hipStream_t stream)
{
  (void)in_sizes; (void)n_in; (void)out_size; (void)ws_size;
  const float* x   = (const float*)d_in[0];
  const float* w1  = (const float*)d_in[2];
  const float* b1  = (const float*)d_in[3];
  const float* w2  = (const float*)d_in[4];
  const float* b2  = (const float*)d_in[5];
  const float* w3  = (const float*)d_in[6];
  const float* b3  = (const float*)d_in[7];
  const float* wm  = (const float*)d_in[8];
  const float* bm  = (const float*)d_in[9];
  const float* wn  = (const float*)d_in[10];
  const float* bn  = (const float*)d_in[11];
  const float* wsc = (const float*)d_in[12];
  const float* bsc = (const float*)d_in[13];
  const float* pm  = (const float*)d_in[14];
  const float* pn  = (const float*)d_in[15];
  const float* psh = (const float*)d_in[16];
  const float* psc = (const float*)d_in[17];
  float* out = (float*)d_out;
  char* ws = (char*)d_ws;

  int*   wp  = (int*)(ws + 0);
  int*   shv = (int*)(ws + 1024);
  float* z   = (float*)(ws + 2048);
  float* h1  = (float*)(ws + 67584);
  float* h2  = (float*)(ws + 198656);
  float* h3  = (float*)(ws + 460800);
  float* scl = (float*)(ws + 722944);

  k_init <<<dim3(64),   dim3(256), 0, stream>>>(z, wp, shv, psh);
  k_mlp1 <<<dim3(256),  dim3(128), 0, stream>>>(z, w1, b1, h1);
  k_mlp2 <<<dim3(256),  dim3(256), 0, stream>>>(h1, w2, b2, h2);
  k_mlp3 <<<dim3(256),  dim3(256), 0, stream>>>(h2, w3, b3, h3);
  k_scale<<<dim3(64),   dim3(256), 0, stream>>>(h3, wsc, bsc, psc, scl);
  k_freq <<<dim3(2048), dim3(256), 0, stream>>>(x, out, psh);
  k_big  <<<dim3(512, 2), dim3(256), 0, stream>>>(x, wm, bm, wn, bn, h3, scl,
                                                  wp, shv, pm, pn, psh, out);
}

// Round 3
// 371.870 us; speedup vs baseline: 1.2152x; 1.1592x over previous
//
#include <hip/hip_runtime.h>
#include <cstdint>
#include <cstddef>

// ============================================================================
// MaskGenerator R3: split k_big -> k_gemm (bf16 MFMA dual-GEMM -> bf16 logits)
//                   + k_fuse (FFT + full augmentation epilogue, all-LDS slab).
// PRNG: threefry2x32 partitionable (validated R1/R2).
// ============================================================================

typedef unsigned int u32;
typedef unsigned short u16;

#define Bd 256
#define Ld 512
#define Fd 64
#define Nd 32768            // Ld*Fd

struct U2 { u32 a, b; };

__device__ __forceinline__ u32 rotl32(u32 x, int r){ return (x << r) | (x >> (32 - r)); }

__device__ __forceinline__ U2 tf2x32(u32 k0, u32 k1, u32 x0, u32 x1){
  u32 ks2 = k0 ^ k1 ^ 0x1BD11BDAu;
  x0 += k0; x1 += k1;
#define TFR4(r0,r1,r2,r3) \
  x0 += x1; x1 = rotl32(x1, r0); x1 ^= x0; \
  x0 += x1; x1 = rotl32(x1, r1); x1 ^= x0; \
  x0 += x1; x1 = rotl32(x1, r2); x1 ^= x0; \
  x0 += x1; x1 = rotl32(x1, r3); x1 ^= x0;
  TFR4(13,15,26,6)  x0 += k1;  x1 += ks2 + 1u;
  TFR4(17,29,16,24) x0 += ks2; x1 += k0 + 2u;
  TFR4(13,15,26,6)  x0 += k0;  x1 += k1 + 3u;
  TFR4(17,29,16,24) x0 += k1;  x1 += ks2 + 4u;
  TFR4(13,15,26,6)  x0 += ks2; x1 += k0 + 5u;
#undef TFR4
  U2 r; r.a = x0; r.b = x1; return r;
}

__device__ __forceinline__ u32 rb32(u32 k0, u32 k1, u32 i){
  U2 r = tf2x32(k0, k1, 0u, i);
  return r.a ^ r.b;
}

__device__ __forceinline__ U2 split_key(u32 k0, u32 k1, u32 j){
  return tf2x32(k0, k1, 0u, j);
}

__device__ __forceinline__ float sigmoidf_(float x){ return 1.0f / (1.0f + expf(-x)); }
__device__ __forceinline__ float softplusf_(float x){ return fmaxf(x, 0.0f) + log1pf(expf(-fabsf(x))); }
__device__ __forceinline__ float leakyf_(float x){ return (x > 0.0f) ? x : 0.2f * x; }

__device__ __forceinline__ float erfinvf_(float x){
  float w = -log1pf(-x * x);
  float p;
  if (w < 5.0f){
    w -= 2.5f;
    p =               2.81022636e-08f;
    p = fmaf(p, w,    3.43273939e-07f);
    p = fmaf(p, w,   -3.5233877e-06f);
    p = fmaf(p, w,   -4.39150654e-06f);
    p = fmaf(p, w,    0.00021858087f);
    p = fmaf(p, w,   -0.00125372503f);
    p = fmaf(p, w,   -0.00417768164f);
    p = fmaf(p, w,    0.246640727f);
    p = fmaf(p, w,    1.50140941f);
  } else {
    w = sqrtf(w) - 3.0f;
    p =              -0.000200214257f;
    p = fmaf(p, w,    0.000100950558f);
    p = fmaf(p, w,    0.00134934322f);
    p = fmaf(p, w,   -0.00367342844f);
    p = fmaf(p, w,    0.00573950773f);
    p = fmaf(p, w,   -0.0076224613f);
    p = fmaf(p, w,    0.00943887047f);
    p = fmaf(p, w,    1.00167406f);
    p = fmaf(p, w,    2.83297682f);
  }
  return p * x;
}

__device__ __forceinline__ float uniform_from_bits(u32 bits){
  return __uint_as_float((bits >> 9) | 0x3f800000u) - 1.0f;
}

__device__ __forceinline__ float normal_from_bits(u32 bits){
  float u01 = uniform_from_bits(bits);
  const float lo = -0.99999994f;
  float v = fmaf(u01, 2.0f, lo);
  v = fmaxf(lo, v);
  return 1.41421356f * erfinvf_(v);
}

__device__ __forceinline__ int warp_idx_(int t, int wp, int sh){
  int tps = t + sh;
  int pos = (t >= wp) ? ((tps < Ld - 1) ? tps : (Ld - 1)) : t;
  int neg = ((t >= wp + sh) && (t < Ld + sh)) ? (t - sh) : t;
  return (sh > 0) ? pos : ((sh < 0) ? neg : t);
}

// f32 -> bf16 RNE
__device__ __forceinline__ u32 pack_bf16_2(float a, float b){
  u32 ua = __float_as_uint(a), ub = __float_as_uint(b);
  u32 ra = (ua + 0x7FFFu + ((ua >> 16) & 1u)) >> 16;
  u32 rb = (ub + 0x7FFFu + ((ub >> 16) & 1u)) >> 16;
  return (ra & 0xFFFFu) | (rb << 16);
}
__device__ __forceinline__ u16 f2bf(float a){
  u32 ua = __float_as_uint(a);
  return (u16)((ua + 0x7FFFu + ((ua >> 16) & 1u)) >> 16);
}
__device__ __forceinline__ float bf2f(u16 v){
  return __uint_as_float(((u32)v) << 16);
}

// LDS k-group swizzle: f(v) in 0..7, gives conflict-free 8-lane phases
__device__ __forceinline__ int swz_(int v){
  return ((v >> 2) & 7) ^ ((v & 3) << 1);
}

// ---------------------------------------------------------------------------
// K0: z normals + wp/sh randint draws (unchanged, validated)
// ---------------------------------------------------------------------------
__global__ __launch_bounds__(256) void k_init(float* __restrict__ z, int* __restrict__ wp,
                                              int* __restrict__ shv, const float* __restrict__ p_shift){
  int gid = blockIdx.x * 256 + threadIdx.x;
  U2 kz = split_key(0u, 42u, 0u);
  z[gid] = normal_from_bits(rb32(kz.a, kz.b, (u32)gid));
  if (blockIdx.x == 0){
    int b = threadIdx.x;
    float s_shift = sigmoidf_(p_shift[0]);
    int wsteps = (int)(51.2f * s_shift);
    U2 kwp = split_key(0u, 42u, 2u);
    U2 ksh = split_key(0u, 42u, 3u);
    {
      U2 k1 = split_key(kwp.a, kwp.b, 0u);
      U2 k2 = split_key(kwp.a, kwp.b, 1u);
      u32 hi = rb32(k1.a, k1.b, (u32)b);
      u32 lo = rb32(k2.a, k2.b, (u32)b);
      u32 span = (u32)(Ld - 2 * wsteps);
      u32 mult = 65536u % span; mult = (mult * mult) % span;
      u32 off = ((hi % span) * mult + (lo % span)) % span;
      wp[b] = wsteps + (int)off;
    }
    {
      U2 k1 = split_key(ksh.a, ksh.b, 0u);
      U2 k2 = split_key(ksh.a, ksh.b, 1u);
      u32 hi = rb32(k1.a, k1.b, (u32)b);
      u32 lo = rb32(k2.a, k2.b, (u32)b);
      u32 span = (u32)(2 * wsteps + 1);
      u32 mult = 65536u % span; mult = (mult * mult) % span;
      u32 off = ((hi % span) * mult + (lo % span)) % span;
      shv[b] = -wsteps + (int)off;
    }
  }
}

// ---------------------------------------------------------------------------
// MLP chain. h3 now stored as bf16 [b][256] (GEMM A-operand format).
// ---------------------------------------------------------------------------
__global__ __launch_bounds__(128) void k_mlp1(const float* __restrict__ z, const float* __restrict__ w1,
                                              const float* __restrict__ b1, float* __restrict__ h1){
  int b = blockIdx.x, n = threadIdx.x;
  const float* zr = z + b * 64;
  float acc = b1[n];
  #pragma unroll 8
  for (int k = 0; k < 64; ++k) acc = fmaf(zr[k], w1[k * 128 + n], acc);
  h1[b * 128 + n] = leakyf_(acc);
}

__global__ __launch_bounds__(256) void k_mlp2(const float* __restrict__ h1, const float* __restrict__ w2,
                                              const float* __restrict__ b2, float* __restrict__ h2){
  int b = blockIdx.x, n = threadIdx.x;
  const float* hr = h1 + b * 128;
  float acc = b2[n];
  #pragma unroll 8
  for (int k = 0; k < 128; ++k) acc = fmaf(hr[k], w2[k * 256 + n], acc);
  h2[b * 256 + n] = leakyf_(acc);
}

__global__ __launch_bounds__(256) void k_mlp3(const float* __restrict__ h2, const float* __restrict__ w3,
                                              const float* __restrict__ b3, u16* __restrict__ h3b){
  int b = blockIdx.x, n = threadIdx.x;
  const float* hr = h2 + b * 256;
  float acc = b3[n];
  #pragma unroll 8
  for (int k = 0; k < 256; ++k) acc = fmaf(hr[k], w3[k * 256 + n], acc);
  h3b[b * 256 + n] = f2bf(leakyf_(acc));
}

__global__ __launch_bounds__(256) void k_scale(const u16* __restrict__ h3b, const float* __restrict__ wsc,
                                               const float* __restrict__ bsc, const float* __restrict__ p_scale,
                                               float* __restrict__ scl){
  int tid = threadIdx.x;
  int b = blockIdx.x * 4 + (tid >> 6);
  int f = tid & 63;
  float acc = bsc[f];
  for (int k = 0; k < 256; ++k) acc = fmaf(bf2f(h3b[b * 256 + k]), wsc[k * 64 + f], acc);
  float s_scale = sigmoidf_(p_scale[0]);
  scl[b * 64 + f] = 1.0f + (softplusf_(acc) - 0.5f) * 0.2f * s_scale;
}

// ---------------------------------------------------------------------------
// k_gemm: dual bf16 MFMA GEMM, C = h3 (256x256) x {wm,wn} (256x32768) + bias,
// output bf16 logits. Block tile 128m x 128n, BK=64, 4 waves (2x2 of 64x64).
// LDS: A[row][kdword] pitch 32, B[n][kdword] pitch 32, XOR-swizzled k-groups.
// ---------------------------------------------------------------------------
typedef short short8 __attribute__((ext_vector_type(8)));
typedef float f32x4 __attribute__((ext_vector_type(4)));
union Frag { uint4 u; short8 s; };

__global__ __launch_bounds__(256, 2) void k_gemm(
    const u16* __restrict__ h3b,
    const float* __restrict__ wm, const float* __restrict__ bm,
    const float* __restrict__ wn, const float* __restrict__ bn,
    u16* __restrict__ logM, u16* __restrict__ logN)
{
  __shared__ __align__(16) u32 As [128 * 32];
  __shared__ __align__(16) u32 Bs0[128 * 32];
  __shared__ __align__(16) u32 Bs1[128 * 32];

  const int tid  = threadIdx.x;
  const int lane = tid & 63;
  const int w    = tid >> 6;
  const int q    = lane >> 4;
  const int lo   = lane & 15;
  const int nt0  = blockIdx.x << 7;     // 128-wide n tile
  const int b0   = blockIdx.y << 7;     // 128-wide m tile
  const int wr   = (w >> 1) << 6;       // wave m offset 0/64
  const int wc   = (w & 1) << 6;        // wave n offset 0/64

  // B staging decomposition
  const int p  = lane >> 3;             // 0..7
  const int c8 = lane & 7;              // 0..7
  const int nb = (w << 5) + (p << 2);   // n base 0..124

  f32x4 accm[4][4], accn[4][4];
  #pragma unroll
  for (int i = 0; i < 4; ++i)
    #pragma unroll
    for (int j = 0; j < 4; ++j){ accm[i][j] = (f32x4)0.0f; accn[i][j] = (f32x4)0.0f; }

  for (int kc = 0; kc < 256; kc += 64){
    if (kc) __syncthreads();
    // ---- stage A: h3b [row][k] bf16, copy 16B groups with swizzle ----
    #pragma unroll
    for (int j = 0; j < 4; ++j){
      int idx  = j * 256 + tid;
      int row  = idx >> 3;
      int slot = idx & 7;
      int g    = slot ^ swz_(row);
      uint4 v  = *(const uint4*)(h3b + (size_t)(b0 + row) * 256 + kc + g * 8);
      *(uint4*)&As[row * 32 + slot * 4] = v;
    }
    // ---- stage B: wm/wn [k][n] -> [n][kdword] bf16, swizzled ----
    #pragma unroll
    for (int cp = 0; cp < 4; ++cp){
      int c = cp * 8 + c8;                        // dword col 0..31
      size_t gb = (size_t)(kc + 2 * c) * Nd + nt0 + nb;
      float4 m0 = *(const float4*)(wm + gb);
      float4 m1 = *(const float4*)(wm + gb + Nd);
      float4 v0 = *(const float4*)(wn + gb);
      float4 v1 = *(const float4*)(wn + gb + Nd);
      int g = c >> 2, cl = c & 3;
      #pragma unroll
      for (int s = 0; s < 4; ++s){
        int n = nb + s;
        int addr = n * 32 + (g ^ swz_(n)) * 4 + cl;
        float a0 = (s == 0) ? m0.x : (s == 1) ? m0.y : (s == 2) ? m0.z : m0.w;
        float a1 = (s == 0) ? m1.x : (s == 1) ? m1.y : (s == 2) ? m1.z : m1.w;
        float b0f = (s == 0) ? v0.x : (s == 1) ? v0.y : (s == 2) ? v0.z : v0.w;
        float b1f = (s == 0) ? v1.x : (s == 1) ? v1.y : (s == 2) ? v1.z : v1.w;
        Bs0[addr] = pack_bf16_2(a0, a1);
        Bs1[addr] = pack_bf16_2(b0f, b1f);
      }
    }
    __syncthreads();

    // ---- MFMA: 2 K32-steps per chunk ----
    #pragma unroll
    for (int u = 0; u < 2; ++u){
      int G = u * 4 + q;
      Frag af[4], bfm[4], bfn[4];
      #pragma unroll
      for (int mt = 0; mt < 4; ++mt){
        int row = wr + mt * 16 + lo;
        af[mt].u = *(const uint4*)&As[row * 32 + (G ^ swz_(row)) * 4];
      }
      #pragma unroll
      for (int nt = 0; nt < 4; ++nt){
        int n = wc + nt * 16 + lo;
        int ad = n * 32 + (G ^ swz_(n)) * 4;
        bfm[nt].u = *(const uint4*)&Bs0[ad];
        bfn[nt].u = *(const uint4*)&Bs1[ad];
      }
      #pragma unroll
      for (int mt = 0; mt < 4; ++mt){
        #pragma unroll
        for (int nt = 0; nt < 4; ++nt){
          accm[mt][nt] = __builtin_amdgcn_mfma_f32_16x16x32_bf16(af[mt].s, bfm[nt].s, accm[mt][nt], 0, 0, 0);
          accn[mt][nt] = __builtin_amdgcn_mfma_f32_16x16x32_bf16(af[mt].s, bfn[nt].s, accn[mt][nt], 0, 0, 0);
        }
      }
    }
  }

  // ---- epilogue: add bias (f32), store bf16 logits ----
  #pragma unroll
  for (int nt = 0; nt < 4; ++nt){
    int n = nt0 + wc + nt * 16 + lo;
    float bmv = bm[n];
    float bnv = bn[n];
    #pragma unroll
    for (int mt = 0; mt < 4; ++mt){
      #pragma unroll
      for (int r = 0; r < 4; ++r){
        int b = b0 + wr + mt * 16 + q * 4 + r;
        size_t o = (size_t)b * Nd + n;
        logM[o] = f2bf(accm[mt][nt][r] + bmv);
        logN[o] = f2bf(accn[mt][nt][r] + bnv);
      }
    }
  }
}

// ---------------------------------------------------------------------------
// k_fuse: FFT + spectral dropout + full augmentation epilogue.
// Block = (b, f-tile of 8). x slab kept pristine in xs[] for straight+warped
// reads; freq computed in a[]; logits/scl/wp/sh streamed in; out written once.
// ---------------------------------------------------------------------------
__global__ __launch_bounds__(256) void k_fuse(
    const float* __restrict__ x,
    const u16* __restrict__ logM, const u16* __restrict__ logN,
    const float* __restrict__ scl,
    const int* __restrict__ wp, const int* __restrict__ shv,
    const float* __restrict__ p_mask, const float* __restrict__ p_noise,
    const float* __restrict__ p_shift,
    float* __restrict__ out)
{
  __shared__ float  xs[8][520];
  __shared__ float2 a[8][514];
  __shared__ float2 tw[256];
  const int tid = threadIdx.x;
  const int b   = blockIdx.x >> 3;
  const int f0  = (blockIdx.x & 7) << 3;

  float s_mask  = sigmoidf_(p_mask[0]);
  float s_noise = sigmoidf_(p_noise[0]);
  float s_shift = sigmoidf_(p_shift[0]);
  float s_mix   = 1.0f - s_shift;
  float ratio   = fminf(s_mix * 0.1f, 0.5f);
  float wa = 1.0f - s_mix - s_shift;
  wa = fminf(fmaxf(wa, 0.1f), 0.8f);
  float wb = s_mix * 0.5f;
  float wc = s_shift * 0.5f;
  float tot = wa + wb + wc;
  wa /= tot; wb /= tot; wc /= tot;
  bool pass = (s_mix < 0.01f);

  U2 kf  = split_key(0u, 42u, 4u);
  U2 knk = split_key(0u, 42u, 1u);
  const int wpb = wp[b];
  const int shb = shv[b];

  {
    float ang = -6.283185307179586f * ((float)tid / 512.0f);
    tw[tid] = make_float2(cosf(ang), sinf(ang));
  }
  const float* xb = x + ((size_t)b * Ld) * Fd + f0;
  for (int idx = tid; idx < 4096; idx += 256){
    int t = idx >> 3, ff = idx & 7;
    float v = xb[t * Fd + ff];
    xs[ff][t] = v;
    a[ff][t] = make_float2(v, 0.0f);
  }
  __syncthreads();

  // forward DIF
  for (int s = 9; s >= 1; --s){
    int half = 1 << (s - 1);
    for (int idx = tid; idx < 2048; idx += 256){
      int ser = idx >> 8, bi = idx & 255;
      int pos = bi & (half - 1);
      int g = bi >> (s - 1);
      int i1 = (g << s) + pos;
      int i2 = i1 + half;
      float2 u = a[ser][i1], v = a[ser][i2];
      a[ser][i1] = make_float2(u.x + v.x, u.y + v.y);
      float dx = u.x - v.x, dy = u.y - v.y;
      float2 wtw = tw[pos << (9 - s)];
      a[ser][i2] = make_float2(dx * wtw.x - dy * wtw.y, dx * wtw.y + dy * wtw.x);
    }
    __syncthreads();
  }

  // spectral dropout (position p holds X[rev9(p)])
  for (int idx = tid; idx < 4096; idx += 256){
    int ser = idx >> 9, pp = idx & 511;
    int k = (int)(__brev((u32)pp) >> 23);
    u32 cnt = (u32)(((b * Ld) + k) * Fd + f0 + ser);
    float u01 = uniform_from_bits(rb32(kf.a, kf.b, cnt));
    if (!(u01 > ratio)) a[ser][pp] = make_float2(0.0f, 0.0f);
  }
  __syncthreads();

  // inverse DIT
  for (int s = 1; s <= 9; ++s){
    int half = 1 << (s - 1);
    for (int idx = tid; idx < 2048; idx += 256){
      int ser = idx >> 8, bi = idx & 255;
      int pos = bi & (half - 1);
      int g = bi >> (s - 1);
      int i1 = (g << s) + pos;
      int i2 = i1 + half;
      float2 wtw = tw[pos << (9 - s)];
      float2 v = a[ser][i2];
      float tx_ = v.x * wtw.x + v.y * wtw.y;
      float ty_ = v.y * wtw.x - v.x * wtw.y;
      float2 u = a[ser][i1];
      a[ser][i1] = make_float2(u.x + tx_, u.y + ty_);
      a[ser][i2] = make_float2(u.x - tx_, u.y - ty_);
    }
    __syncthreads();
  }

  // fused augmentation epilogue
  const u16* lMb = logM + (size_t)b * Nd;
  const u16* lNb = logN + (size_t)b * Nd;
  float* ob = out + ((size_t)b * Ld) * Fd;
  for (int idx = tid; idx < 4096; idx += 256){
    int t = idx >> 3, ff = idx & 7;
    int f = f0 + ff;
    int nidx = t * Fd + f;
    float xv = xs[ff][t];
    int wi = warp_idx_(t, wpb, shb);
    float wv = xs[ff][wi];
    float fq = pass ? xv : (a[ff][t].x * (1.0f / 512.0f));
    float sc = scl[b * 64 + f];
    float maskv = sigmoidf_(bf2f(lMb[nidx]));
    maskv = 1.0f - (1.0f - maskv) * s_mask * 0.3f;
    float nmag = softplusf_(bf2f(lNb[nidx]));
    u32 cnt = (u32)(b * Nd + nidx);
    float nr = normal_from_bits(rb32(knk.a, knk.b, cnt));
    float noise = nr * nmag * s_noise * 0.05f;
    float aug = fmaf(xv * maskv, sc, noise);
    ob[nidx] = aug * wa + fq * wb + wv * wc;
  }
}

// ---------------------------------------------------------------------------
extern "C" void kernel_launch(void* const* d_in, const int* in_sizes, int n_in,
                              void* d_out, int out_size, void* d_ws, size_t ws_size,
                              hipStream_t stream)
{
  (void)in_sizes; (void)n_in; (void)out_size; (void)ws_size;
  const float* x   = (const float*)d_in[0];
  const float* w1  = (const float*)d_in[2];
  const float* b1  = (const float*)d_in[3];
  const float* w2  = (const float*)d_in[4];
  const float* b2  = (const float*)d_in[5];
  const float* w3  = (const float*)d_in[6];
  const float* b3  = (const float*)d_in[7];
  const float* wm  = (const float*)d_in[8];
  const float* bm  = (const float*)d_in[9];
  const float* wn  = (const float*)d_in[10];
  const float* bn  = (const float*)d_in[11];
  const float* wsc = (const float*)d_in[12];
  const float* bsc = (const float*)d_in[13];
  const float* pm  = (const float*)d_in[14];
  const float* pn  = (const float*)d_in[15];
  const float* psh = (const float*)d_in[16];
  const float* psc = (const float*)d_in[17];
  float* out = (float*)d_out;
  char* ws = (char*)d_ws;

  // ws layout (bytes):
  int*   wp   = (int*)(ws + 0);            // 1 KB
  int*   shv  = (int*)(ws + 1024);         // 1 KB
  float* z    = (float*)(ws + 2048);       // 64 KB
  float* h1   = (float*)(ws + 67584);      // 128 KB
  float* h2   = (float*)(ws + 198656);     // 256 KB
  u16*   h3b  = (u16*)  (ws + 460800);     // 128 KB
  float* scl  = (float*)(ws + 591872);     // 64 KB
  u16*   logM = (u16*)  (ws + 1048576);    // 16 MB
  u16*   logN = (u16*)  (ws + 1048576 + 16777216);  // 16 MB  (total ~33.8 MB)

  k_init <<<dim3(64),      dim3(256), 0, stream>>>(z, wp, shv, psh);
  k_mlp1 <<<dim3(256),     dim3(128), 0, stream>>>(z, w1, b1, h1);
  k_mlp2 <<<dim3(256),     dim3(256), 0, stream>>>(h1, w2, b2, h2);
  k_mlp3 <<<dim3(256),     dim3(256), 0, stream>>>(h2, w3, b3, h3b);
  k_scale<<<dim3(64),      dim3(256), 0, stream>>>(h3b, wsc, bsc, psc, scl);
  k_gemm <<<dim3(256, 2),  dim3(256), 0, stream>>>(h3b, wm, bm, wn, bn, logM, logN);
  k_fuse <<<dim3(2048),    dim3(256), 0, stream>>>(x, logM, logN, scl, wp, shv,
                                                   pm, pn, psh, out);
}

// Round 4
// 327.325 us; speedup vs baseline: 1.3805x; 1.1361x over previous
//
#include <hip/hip_runtime.h>
#include <cstdint>
#include <cstddef>

// ============================================================================
// MaskGenerator R4: k_fuse -> k_faug (real-pair-packed FFT: 2 features per
// complex series; Hermitian-part identity for the masked inverse; SoA LDS,
// odd pitch + swizzle; 16-feature blocks at 4 blocks/CU).
// k_gemm/MLP chain unchanged from R3 (validated). PRNG: threefry2x32
// partitionable (validated R1-R3).
// ============================================================================

typedef unsigned int u32;
typedef unsigned short u16;

#define Bd 256
#define Ld 512
#define Fd 64
#define Nd 32768            // Ld*Fd

struct U2 { u32 a, b; };

__device__ __forceinline__ u32 rotl32(u32 x, int r){ return (x << r) | (x >> (32 - r)); }

__device__ __forceinline__ U2 tf2x32(u32 k0, u32 k1, u32 x0, u32 x1){
  u32 ks2 = k0 ^ k1 ^ 0x1BD11BDAu;
  x0 += k0; x1 += k1;
#define TFR4(r0,r1,r2,r3) \
  x0 += x1; x1 = rotl32(x1, r0); x1 ^= x0; \
  x0 += x1; x1 = rotl32(x1, r1); x1 ^= x0; \
  x0 += x1; x1 = rotl32(x1, r2); x1 ^= x0; \
  x0 += x1; x1 = rotl32(x1, r3); x1 ^= x0;
  TFR4(13,15,26,6)  x0 += k1;  x1 += ks2 + 1u;
  TFR4(17,29,16,24) x0 += ks2; x1 += k0 + 2u;
  TFR4(13,15,26,6)  x0 += k0;  x1 += k1 + 3u;
  TFR4(17,29,16,24) x0 += k1;  x1 += ks2 + 4u;
  TFR4(13,15,26,6)  x0 += ks2; x1 += k0 + 5u;
#undef TFR4
  U2 r; r.a = x0; r.b = x1; return r;
}

__device__ __forceinline__ u32 rb32(u32 k0, u32 k1, u32 i){
  U2 r = tf2x32(k0, k1, 0u, i);
  return r.a ^ r.b;
}

__device__ __forceinline__ U2 split_key(u32 k0, u32 k1, u32 j){
  return tf2x32(k0, k1, 0u, j);
}

__device__ __forceinline__ float sigmoidf_(float x){ return 1.0f / (1.0f + expf(-x)); }
__device__ __forceinline__ float softplusf_(float x){ return fmaxf(x, 0.0f) + log1pf(expf(-fabsf(x))); }
__device__ __forceinline__ float leakyf_(float x){ return (x > 0.0f) ? x : 0.2f * x; }

__device__ __forceinline__ float erfinvf_(float x){
  float w = -log1pf(-x * x);
  float p;
  if (w < 5.0f){
    w -= 2.5f;
    p =               2.81022636e-08f;
    p = fmaf(p, w,    3.43273939e-07f);
    p = fmaf(p, w,   -3.5233877e-06f);
    p = fmaf(p, w,   -4.39150654e-06f);
    p = fmaf(p, w,    0.00021858087f);
    p = fmaf(p, w,   -0.00125372503f);
    p = fmaf(p, w,   -0.00417768164f);
    p = fmaf(p, w,    0.246640727f);
    p = fmaf(p, w,    1.50140941f);
  } else {
    w = sqrtf(w) - 3.0f;
    p =              -0.000200214257f;
    p = fmaf(p, w,    0.000100950558f);
    p = fmaf(p, w,    0.00134934322f);
    p = fmaf(p, w,   -0.00367342844f);
    p = fmaf(p, w,    0.00573950773f);
    p = fmaf(p, w,   -0.0076224613f);
    p = fmaf(p, w,    0.00943887047f);
    p = fmaf(p, w,    1.00167406f);
    p = fmaf(p, w,    2.83297682f);
  }
  return p * x;
}

__device__ __forceinline__ float uniform_from_bits(u32 bits){
  return __uint_as_float((bits >> 9) | 0x3f800000u) - 1.0f;
}

__device__ __forceinline__ float normal_from_bits(u32 bits){
  float u01 = uniform_from_bits(bits);
  const float lo = -0.99999994f;
  float v = fmaf(u01, 2.0f, lo);
  v = fmaxf(lo, v);
  return 1.41421356f * erfinvf_(v);
}

__device__ __forceinline__ int warp_idx_(int t, int wp, int sh){
  int tps = t + sh;
  int pos = (t >= wp) ? ((tps < Ld - 1) ? tps : (Ld - 1)) : t;
  int neg = ((t >= wp + sh) && (t < Ld + sh)) ? (t - sh) : t;
  return (sh > 0) ? pos : ((sh < 0) ? neg : t);
}

__device__ __forceinline__ u32 pack_bf16_2(float a, float b){
  u32 ua = __float_as_uint(a), ub = __float_as_uint(b);
  u32 ra = (ua + 0x7FFFu + ((ua >> 16) & 1u)) >> 16;
  u32 rb = (ub + 0x7FFFu + ((ub >> 16) & 1u)) >> 16;
  return (ra & 0xFFFFu) | (rb << 16);
}
__device__ __forceinline__ u16 f2bf(float a){
  u32 ua = __float_as_uint(a);
  return (u16)((ua + 0x7FFFu + ((ua >> 16) & 1u)) >> 16);
}
__device__ __forceinline__ float bf2f(u16 v){
  return __uint_as_float(((u32)v) << 16);
}

__device__ __forceinline__ int swz_(int v){
  return ((v >> 2) & 7) ^ ((v & 3) << 1);
}
__device__ __forceinline__ int rev9_(int k){
  return (int)(__brev((u32)k) >> 23);
}

// ---------------------------------------------------------------------------
// K0: z normals + wp/sh randint draws (validated)
// ---------------------------------------------------------------------------
__global__ __launch_bounds__(256) void k_init(float* __restrict__ z, int* __restrict__ wp,
                                              int* __restrict__ shv, const float* __restrict__ p_shift){
  int gid = blockIdx.x * 256 + threadIdx.x;
  U2 kz = split_key(0u, 42u, 0u);
  z[gid] = normal_from_bits(rb32(kz.a, kz.b, (u32)gid));
  if (blockIdx.x == 0){
    int b = threadIdx.x;
    float s_shift = sigmoidf_(p_shift[0]);
    int wsteps = (int)(51.2f * s_shift);
    U2 kwp = split_key(0u, 42u, 2u);
    U2 ksh = split_key(0u, 42u, 3u);
    {
      U2 k1 = split_key(kwp.a, kwp.b, 0u);
      U2 k2 = split_key(kwp.a, kwp.b, 1u);
      u32 hi = rb32(k1.a, k1.b, (u32)b);
      u32 lo = rb32(k2.a, k2.b, (u32)b);
      u32 span = (u32)(Ld - 2 * wsteps);
      u32 mult = 65536u % span; mult = (mult * mult) % span;
      u32 off = ((hi % span) * mult + (lo % span)) % span;
      wp[b] = wsteps + (int)off;
    }
    {
      U2 k1 = split_key(ksh.a, ksh.b, 0u);
      U2 k2 = split_key(ksh.a, ksh.b, 1u);
      u32 hi = rb32(k1.a, k1.b, (u32)b);
      u32 lo = rb32(k2.a, k2.b, (u32)b);
      u32 span = (u32)(2 * wsteps + 1);
      u32 mult = 65536u % span; mult = (mult * mult) % span;
      u32 off = ((hi % span) * mult + (lo % span)) % span;
      shv[b] = -wsteps + (int)off;
    }
  }
}

// ---------------------------------------------------------------------------
// MLP chain (validated)
// ---------------------------------------------------------------------------
__global__ __launch_bounds__(128) void k_mlp1(const float* __restrict__ z, const float* __restrict__ w1,
                                              const float* __restrict__ b1, float* __restrict__ h1){
  int b = blockIdx.x, n = threadIdx.x;
  const float* zr = z + b * 64;
  float acc = b1[n];
  #pragma unroll 8
  for (int k = 0; k < 64; ++k) acc = fmaf(zr[k], w1[k * 128 + n], acc);
  h1[b * 128 + n] = leakyf_(acc);
}

__global__ __launch_bounds__(256) void k_mlp2(const float* __restrict__ h1, const float* __restrict__ w2,
                                              const float* __restrict__ b2, float* __restrict__ h2){
  int b = blockIdx.x, n = threadIdx.x;
  const float* hr = h1 + b * 128;
  float acc = b2[n];
  #pragma unroll 8
  for (int k = 0; k < 128; ++k) acc = fmaf(hr[k], w2[k * 256 + n], acc);
  h2[b * 256 + n] = leakyf_(acc);
}

__global__ __launch_bounds__(256) void k_mlp3(const float* __restrict__ h2, const float* __restrict__ w3,
                                              const float* __restrict__ b3, u16* __restrict__ h3b){
  int b = blockIdx.x, n = threadIdx.x;
  const float* hr = h2 + b * 256;
  float acc = b3[n];
  #pragma unroll 8
  for (int k = 0; k < 256; ++k) acc = fmaf(hr[k], w3[k * 256 + n], acc);
  h3b[b * 256 + n] = f2bf(leakyf_(acc));
}

__global__ __launch_bounds__(256) void k_scale(const u16* __restrict__ h3b, const float* __restrict__ wsc,
                                               const float* __restrict__ bsc, const float* __restrict__ p_scale,
                                               float* __restrict__ scl){
  int tid = threadIdx.x;
  int b = blockIdx.x * 4 + (tid >> 6);
  int f = tid & 63;
  float acc = bsc[f];
  for (int k = 0; k < 256; ++k) acc = fmaf(bf2f(h3b[b * 256 + k]), wsc[k * 64 + f], acc);
  float s_scale = sigmoidf_(p_scale[0]);
  scl[b * 64 + f] = 1.0f + (softplusf_(acc) - 0.5f) * 0.2f * s_scale;
}

// ---------------------------------------------------------------------------
// k_gemm: unchanged from R3 (validated)
// ---------------------------------------------------------------------------
typedef short short8 __attribute__((ext_vector_type(8)));
typedef float f32x4 __attribute__((ext_vector_type(4)));
union Frag { uint4 u; short8 s; };

__global__ __launch_bounds__(256, 2) void k_gemm(
    const u16* __restrict__ h3b,
    const float* __restrict__ wm, const float* __restrict__ bm,
    const float* __restrict__ wn, const float* __restrict__ bn,
    u16* __restrict__ logM, u16* __restrict__ logN)
{
  __shared__ __align__(16) u32 As [128 * 32];
  __shared__ __align__(16) u32 Bs0[128 * 32];
  __shared__ __align__(16) u32 Bs1[128 * 32];

  const int tid  = threadIdx.x;
  const int lane = tid & 63;
  const int w    = tid >> 6;
  const int q    = lane >> 4;
  const int lo   = lane & 15;
  const int nt0  = blockIdx.x << 7;
  const int b0   = blockIdx.y << 7;
  const int wr   = (w >> 1) << 6;
  const int wc   = (w & 1) << 6;

  const int p  = lane >> 3;
  const int c8 = lane & 7;
  const int nb = (w << 5) + (p << 2);

  f32x4 accm[4][4], accn[4][4];
  #pragma unroll
  for (int i = 0; i < 4; ++i)
    #pragma unroll
    for (int j = 0; j < 4; ++j){ accm[i][j] = (f32x4)0.0f; accn[i][j] = (f32x4)0.0f; }

  for (int kc = 0; kc < 256; kc += 64){
    if (kc) __syncthreads();
    #pragma unroll
    for (int j = 0; j < 4; ++j){
      int idx  = j * 256 + tid;
      int row  = idx >> 3;
      int slot = idx & 7;
      int g    = slot ^ swz_(row);
      uint4 v  = *(const uint4*)(h3b + (size_t)(b0 + row) * 256 + kc + g * 8);
      *(uint4*)&As[row * 32 + slot * 4] = v;
    }
    #pragma unroll
    for (int cp = 0; cp < 4; ++cp){
      int c = cp * 8 + c8;
      size_t gb = (size_t)(kc + 2 * c) * Nd + nt0 + nb;
      float4 m0 = *(const float4*)(wm + gb);
      float4 m1 = *(const float4*)(wm + gb + Nd);
      float4 v0 = *(const float4*)(wn + gb);
      float4 v1 = *(const float4*)(wn + gb + Nd);
      int g = c >> 2, cl = c & 3;
      #pragma unroll
      for (int s = 0; s < 4; ++s){
        int n = nb + s;
        int addr = n * 32 + (g ^ swz_(n)) * 4 + cl;
        float a0 = (s == 0) ? m0.x : (s == 1) ? m0.y : (s == 2) ? m0.z : m0.w;
        float a1 = (s == 0) ? m1.x : (s == 1) ? m1.y : (s == 2) ? m1.z : m1.w;
        float b0f = (s == 0) ? v0.x : (s == 1) ? v0.y : (s == 2) ? v0.z : v0.w;
        float b1f = (s == 0) ? v1.x : (s == 1) ? v1.y : (s == 2) ? v1.z : v1.w;
        Bs0[addr] = pack_bf16_2(a0, a1);
        Bs1[addr] = pack_bf16_2(b0f, b1f);
      }
    }
    __syncthreads();

    #pragma unroll
    for (int u = 0; u < 2; ++u){
      int G = u * 4 + q;
      Frag af[4], bfm[4], bfn[4];
      #pragma unroll
      for (int mt = 0; mt < 4; ++mt){
        int row = wr + mt * 16 + lo;
        af[mt].u = *(const uint4*)&As[row * 32 + (G ^ swz_(row)) * 4];
      }
      #pragma unroll
      for (int nt = 0; nt < 4; ++nt){
        int n = wc + nt * 16 + lo;
        int ad = n * 32 + (G ^ swz_(n)) * 4;
        bfm[nt].u = *(const uint4*)&Bs0[ad];
        bfn[nt].u = *(const uint4*)&Bs1[ad];
      }
      #pragma unroll
      for (int mt = 0; mt < 4; ++mt){
        #pragma unroll
        for (int nt = 0; nt < 4; ++nt){
          accm[mt][nt] = __builtin_amdgcn_mfma_f32_16x16x32_bf16(af[mt].s, bfm[nt].s, accm[mt][nt], 0, 0, 0);
          accn[mt][nt] = __builtin_amdgcn_mfma_f32_16x16x32_bf16(af[mt].s, bfn[nt].s, accn[mt][nt], 0, 0, 0);
        }
      }
    }
  }

  #pragma unroll
  for (int nt = 0; nt < 4; ++nt){
    int n = nt0 + wc + nt * 16 + lo;
    float bmv = bm[n];
    float bnv = bn[n];
    #pragma unroll
    for (int mt = 0; mt < 4; ++mt){
      #pragma unroll
      for (int r = 0; r < 4; ++r){
        int b = b0 + wr + mt * 16 + q * 4 + r;
        size_t o = (size_t)b * Nd + n;
        logM[o] = f2bf(accm[mt][nt][r] + bmv);
        logN[o] = f2bf(accn[mt][nt][r] + bnv);
      }
    }
  }
}

// ---------------------------------------------------------------------------
// k_faug: packed real-pair FFT + spectral dropout + inverse + full epilogue.
// Block = (b, 16-feature tile) = 8 complex series z_j = x[:,2j] + i x[:,2j+1].
// Forward DIF (natural->bitrev) -> masked Hermitian repack at natural freq k
// (U[k] = m0*X0 + i*m1*X1, exact) -> inverse DIT (bitrev->natural):
// Re = freq of feature 2j, Im = freq of feature 2j+1.
// SoA LDS, pitch 529 (odd), phys(t)=t+(t>>5) swizzle.
// ---------------------------------------------------------------------------
#define PITCH 529

__device__ __forceinline__ int lphys(int t){ return t + (t >> 5); }

__global__ __launch_bounds__(256, 4) void k_faug(
    const float* __restrict__ x,
    const u16* __restrict__ logM, const u16* __restrict__ logN,
    const float* __restrict__ scl,
    const int* __restrict__ wp, const int* __restrict__ shv,
    const float* __restrict__ p_mask, const float* __restrict__ p_noise,
    const float* __restrict__ p_shift,
    float* __restrict__ out)
{
  __shared__ float SR[8 * PITCH];
  __shared__ float SI[8 * PITCH];
  __shared__ float2 tw[256];

  const int tid = threadIdx.x;
  const int b   = blockIdx.x >> 2;
  const int f0  = (blockIdx.x & 3) << 4;

  float s_mask  = sigmoidf_(p_mask[0]);
  float s_noise = sigmoidf_(p_noise[0]);
  float s_shift = sigmoidf_(p_shift[0]);
  float s_mix   = 1.0f - s_shift;
  float ratio   = fminf(s_mix * 0.1f, 0.5f);
  float wa = 1.0f - s_mix - s_shift;
  wa = fminf(fmaxf(wa, 0.1f), 0.8f);
  float wb = s_mix * 0.5f;
  float wc = s_shift * 0.5f;
  float tot = wa + wb + wc;
  wa /= tot; wb /= tot; wc /= tot;
  bool pass = (s_mix < 0.01f);

  U2 kf  = split_key(0u, 42u, 4u);
  U2 knk = split_key(0u, 42u, 1u);
  const int wpb = wp[b];
  const int shb = shv[b];

  {
    float ang = -6.283185307179586f * ((float)tid / 512.0f);
    tw[tid] = make_float2(cosf(ang), sinf(ang));
  }

  // ---- stage in + pack pairs ----
  const float* xb = x + (size_t)b * Nd;
  #pragma unroll
  for (int s = 0; s < 8; ++s){
    int qq = (s << 8) + tid;        // float4 id, 0..2047
    int t  = qq >> 2;
    int f4 = qq & 3;
    float4 v = *(const float4*)(xb + t * 64 + f0 + (f4 << 2));
    int j = f4 << 1;
    int pt = lphys(t);
    SR[j * PITCH + pt]       = v.x;  SI[j * PITCH + pt]       = v.y;
    SR[(j + 1) * PITCH + pt] = v.z;  SI[(j + 1) * PITCH + pt] = v.w;
  }
  __syncthreads();

  // ---- forward DIF (natural in -> bitrev out) ----
  for (int s = 9; s >= 1; --s){
    int half = 1 << (s - 1);
    #pragma unroll
    for (int it = 0; it < 8; ++it){
      int j  = it;                  // one series per sweep; lanes span bfly idx
      int bi = tid;
      int pos = bi & (half - 1);
      int g = bi >> (s - 1);
      int i1 = (g << s) + pos;
      int i2 = i1 + half;
      int a1 = j * PITCH + lphys(i1);
      int a2 = j * PITCH + lphys(i2);
      float ur = SR[a1], ui = SI[a1];
      float vr = SR[a2], vi = SI[a2];
      SR[a1] = ur + vr; SI[a1] = ui + vi;
      float dr = ur - vr, di = ui - vi;
      float2 w = tw[pos << (9 - s)];
      SR[a2] = dr * w.x - di * w.y;
      SI[a2] = dr * w.y + di * w.x;
    }
    __syncthreads();
  }

  // ---- masked Hermitian repack at natural frequency k ----
  // slot k in [0,255]; k=0 also handles k=256 (both self-paired).
  #pragma unroll
  for (int it = 0; it < 8; ++it){
    int j = it;
    int k = tid;
    int nItr = (k == 0) ? 2 : 1;
    for (int e = 0; e < nItr; ++e){
      int kk = (e == 0) ? k : 256;
      int nk = (512 - kk) & 511;
      int pk = rev9_(kk), pn = rev9_(nk);
      int ak = j * PITCH + lphys(pk);
      int an = j * PITCH + lphys(pn);
      float zkr = SR[ak], zki = SI[ak];
      float znr = SR[an], zni = SI[an];
      float X0r = 0.5f * (zkr + znr), X0i = 0.5f * (zki - zni);
      float X1r = 0.5f * (zki + zni), X1i = 0.5f * (znr - zkr);
      int fA = f0 + (j << 1);
      u32 ck = (u32)((b * Ld + kk) * Fd + fA);
      u32 cn = (u32)((b * Ld + nk) * Fd + fA);
      float k0a = (uniform_from_bits(rb32(kf.a, kf.b, ck))      > ratio) ? 1.0f : 0.0f;
      float k0b = (uniform_from_bits(rb32(kf.a, kf.b, cn))      > ratio) ? 1.0f : 0.0f;
      float k1a = (uniform_from_bits(rb32(kf.a, kf.b, ck + 1u)) > ratio) ? 1.0f : 0.0f;
      float k1b = (uniform_from_bits(rb32(kf.a, kf.b, cn + 1u)) > ratio) ? 1.0f : 0.0f;
      float m0 = 0.5f * (k0a + k0b);
      float m1 = 0.5f * (k1a + k1b);
      // U[k] = m0*X0 + i*m1*X1 ; U[nk] = m0*conj(X0) + i*m1*conj(X1)
      SR[ak] = m0 * X0r - m1 * X1i;
      SI[ak] = m0 * X0i + m1 * X1r;
      SR[an] = m0 * X0r + m1 * X1i;
      SI[an] = m1 * X1r - m0 * X0i;
    }
  }
  __syncthreads();

  // ---- inverse DIT (bitrev in -> natural out) ----
  for (int s = 1; s <= 9; ++s){
    int half = 1 << (s - 1);
    #pragma unroll
    for (int it = 0; it < 8; ++it){
      int j  = it;
      int bi = tid;
      int pos = bi & (half - 1);
      int g = bi >> (s - 1);
      int i1 = (g << s) + pos;
      int i2 = i1 + half;
      int a1 = j * PITCH + lphys(i1);
      int a2 = j * PITCH + lphys(i2);
      float2 w = tw[pos << (9 - s)];
      float vr = SR[a2], vi = SI[a2];
      float tx_ = vr * w.x + vi * w.y;    // v * conj(w)
      float ty_ = vi * w.x - vr * w.y;
      float ur = SR[a1], ui = SI[a1];
      SR[a1] = ur + tx_; SI[a1] = ui + ty_;
      SR[a2] = ur - tx_; SI[a2] = ui - ty_;
    }
    __syncthreads();
  }

  // ---- fused augmentation epilogue ----
  const float inv512 = 1.0f / 512.0f;
  const u16* lMb = logM + (size_t)b * Nd;
  const u16* lNb = logN + (size_t)b * Nd;
  float* ob = out + (size_t)b * Nd;
  #pragma unroll
  for (int s = 0; s < 8; ++s){
    int qq = (s << 8) + tid;
    int t  = qq >> 2;
    int f4 = qq & 3;
    int f  = f0 + (f4 << 2);
    int j  = f4 << 1;
    int pt = lphys(t);
    int nidx = t * 64 + f;
    float4 xv = *(const float4*)(xb + nidx);
    int wi = warp_idx_(t, wpb, shb);
    float4 wv = *(const float4*)(xb + wi * 64 + f);
    float4 sc = *(const float4*)(scl + b * 64 + f);
    ushort4 mr = *(const ushort4*)(lMb + nidx);
    ushort4 nr4 = *(const ushort4*)(lNb + nidx);
    float fr[4];
    fr[0] = SR[j * PITCH + pt] * inv512;
    fr[1] = SI[j * PITCH + pt] * inv512;
    fr[2] = SR[(j + 1) * PITCH + pt] * inv512;
    fr[3] = SI[(j + 1) * PITCH + pt] * inv512;
    const float xvv[4] = {xv.x, xv.y, xv.z, xv.w};
    const float wvv[4] = {wv.x, wv.y, wv.z, wv.w};
    const float scv[4] = {sc.x, sc.y, sc.z, sc.w};
    const u16 mrv[4] = {mr.x, mr.y, mr.z, mr.w};
    const u16 nrv[4] = {nr4.x, nr4.y, nr4.z, nr4.w};
    float o[4];
    #pragma unroll
    for (int c = 0; c < 4; ++c){
      float maskv = sigmoidf_(bf2f(mrv[c]));
      maskv = 1.0f - (1.0f - maskv) * s_mask * 0.3f;
      float nmag = softplusf_(bf2f(nrv[c]));
      float nz = normal_from_bits(rb32(knk.a, knk.b, (u32)(b * Nd + nidx + c)));
      float noise = nz * nmag * s_noise * 0.05f;
      float fq = pass ? xvv[c] : fr[c];
      float aug = fmaf(xvv[c] * maskv, scv[c], noise);
      o[c] = aug * wa + fq * wb + wvv[c] * wc;
    }
    *(float4*)(ob + nidx) = make_float4(o[0], o[1], o[2], o[3]);
  }
}

// ---------------------------------------------------------------------------
extern "C" void kernel_launch(void* const* d_in, const int* in_sizes, int n_in,
                              void* d_out, int out_size, void* d_ws, size_t ws_size,
                              hipStream_t stream)
{
  (void)in_sizes; (void)n_in; (void)out_size; (void)ws_size;
  const float* x   = (const float*)d_in[0];
  const float* w1  = (const float*)d_in[2];
  const float* b1  = (const float*)d_in[3];
  const float* w2  = (const float*)d_in[4];
  const float* b2  = (const float*)d_in[5];
  const float* w3  = (const float*)d_in[6];
  const float* b3  = (const float*)d_in[7];
  const float* wm  = (const float*)d_in[8];
  const float* bm  = (const float*)d_in[9];
  const float* wn  = (const float*)d_in[10];
  const float* bn  = (const float*)d_in[11];
  const float* wsc = (const float*)d_in[12];
  const float* bsc = (const float*)d_in[13];
  const float* pm  = (const float*)d_in[14];
  const float* pn  = (const float*)d_in[15];
  const float* psh = (const float*)d_in[16];
  const float* psc = (const float*)d_in[17];
  float* out = (float*)d_out;
  char* ws = (char*)d_ws;

  int*   wp   = (int*)(ws + 0);
  int*   shv  = (int*)(ws + 1024);
  float* z    = (float*)(ws + 2048);
  float* h1   = (float*)(ws + 67584);
  float* h2   = (float*)(ws + 198656);
  u16*   h3b  = (u16*)  (ws + 460800);
  float* scl  = (float*)(ws + 591872);
  u16*   logM = (u16*)  (ws + 1048576);
  u16*   logN = (u16*)  (ws + 1048576 + 16777216);

  k_init <<<dim3(64),      dim3(256), 0, stream>>>(z, wp, shv, psh);
  k_mlp1 <<<dim3(256),     dim3(128), 0, stream>>>(z, w1, b1, h1);
  k_mlp2 <<<dim3(256),     dim3(256), 0, stream>>>(h1, w2, b2, h2);
  k_mlp3 <<<dim3(256),     dim3(256), 0, stream>>>(h2, w3, b3, h3b);
  k_scale<<<dim3(64),      dim3(256), 0, stream>>>(h3b, wsc, bsc, psc, scl);
  k_gemm <<<dim3(256, 2),  dim3(256), 0, stream>>>(h3b, wm, bm, wn, bn, logM, logN);
  k_faug <<<dim3(1024),    dim3(256), 0, stream>>>(x, logM, logN, scl, wp, shv,
                                                   pm, pn, psh, out);
}